// Round 3
// baseline (105.062 us; speedup 1.0000x reference)
//
#include <hip/hip_runtime.h>
#include <float.h>

#define OUTP 7
#define NCH 256
#define FH 50
#define FW 50
#define LDS_W 65   // 64 lanes + 1 pad

// One wave per (roi, channel) pair. Lane = column within ROI region.
__global__ __launch_bounds__(256) void roi_pool_v3(
    const float* __restrict__ features,   // (B,256,50,50)
    const float* __restrict__ cat_rois,   // (N,5): im,x1,y1,x2,y2
    float* __restrict__ out)              // (N,256,7,7)
{
    __shared__ float rowmax[4][OUTP][LDS_W];   // 7280 B

    const int lane = threadIdx.x & 63;
    const int quad = threadIdx.x >> 6;         // wave id in block
    const int n    = blockIdx.x >> 6;          // 64 blocks per ROI
    const int c    = ((blockIdx.x & 63) << 2) + quad;

    const float* r5 = cat_rois + n * 5;
    const int im = (int)rintf(r5[0]);
    const int x1 = (int)rintf(r5[1] * 0.0625f);
    const int y1 = (int)rintf(r5[2] * 0.0625f);
    const int x2 = (int)rintf(r5[3] * 0.0625f);
    const int y2 = (int)rintf(r5[4] * 0.0625f);

    const int h = y2 - y1 + 1;   // region fully in-bounds (clamps are no-ops)
    const int w = x2 - x1 + 1;

    // row-bin boundaries (relative to y1)
    int ys[OUTP], ye[OUTP];
    #pragma unroll
    for (int i = 0; i < OUTP; ++i) {
        ys[i] = i * h / OUTP;
        ye[i] = ((i + 1) * h + OUTP - 1) / OUTP;
    }

    float rm[OUTP];
    #pragma unroll
    for (int i = 0; i < OUTP; ++i) rm[i] = -FLT_MAX;

    const float* base = features + ((size_t)(im * NCH + c)) * (FH * FW)
                                 + y1 * FW + x1;

    // ---- Phase A: coalesced column-wise scan; predicated row-bin folds.
    //      2-row unroll keeps >=2 independent loads in flight. ----
    if (lane < w) {
        int r = 0;
        for (; r + 1 < h; r += 2) {
            float v0 = base[r * FW + lane];
            float v1 = base[(r + 1) * FW + lane];
            #pragma unroll
            for (int i = 0; i < OUTP; ++i) {
                if (r     >= ys[i] && r     < ye[i]) rm[i] = fmaxf(rm[i], v0);
                if (r + 1 >= ys[i] && r + 1 < ye[i]) rm[i] = fmaxf(rm[i], v1);
            }
        }
        if (r < h) {
            float v0 = base[r * FW + lane];
            #pragma unroll
            for (int i = 0; i < OUTP; ++i) {
                if (r >= ys[i] && r < ye[i]) rm[i] = fmaxf(rm[i], v0);
            }
        }
    }

    // ---- tiny transpose through LDS (conflict-free: consecutive lanes
    //      -> consecutive banks; +1 pad breaks i-stride aliasing) ----
    #pragma unroll
    for (int i = 0; i < OUTP; ++i)
        rowmax[quad][i][lane] = rm[i];

    __syncthreads();

    // ---- Phase B: 49 lanes col-pool (~2.5 reads avg, <=8) ----
    if (lane < OUTP * OUTP) {
        const int i  = lane / OUTP;
        const int j  = lane % OUTP;
        const int xs = j * w / OUTP;
        const int xe = ((j + 1) * w + OUTP - 1) / OUTP;   // <= w always

        float m = -FLT_MAX;
        for (int x = xs; x < xe; ++x)
            m = fmaxf(m, rowmax[quad][i][x]);

        out[(((size_t)n * NCH + c) * OUTP + i) * OUTP + j] = m;
    }
}

extern "C" void kernel_launch(void* const* d_in, const int* in_sizes, int n_in,
                              void* d_out, int out_size, void* d_ws, size_t ws_size,
                              hipStream_t stream) {
    const float* features = (const float*)d_in[0];
    const float* cat_rois = (const float*)d_in[1];
    float* out = (float*)d_out;

    const int N = in_sizes[1] / 5;        // 128 ROIs
    dim3 grid(N * (NCH / 4));             // 8192 blocks, 4 waves each
    roi_pool_v3<<<grid, 256, 0, stream>>>(features, cat_rois, out);
}

// Round 4
// 75.754 us; speedup vs baseline: 1.3869x; 1.3869x over previous
//
#include <hip/hip_runtime.h>
#include <float.h>

#define OUTP 7
#define NCH 256
#define FH 50
#define FW 50
#define LDS_W 65   // 64 lanes + 1 pad

// One wave per (roi, channel). Lane = column within ROI region.
// Bin-first loop: 1 fmax per loaded element (no predicated 7-bin fold).
__global__ __launch_bounds__(256) void roi_pool_v4(
    const float* __restrict__ features,   // (B,256,50,50)
    const float* __restrict__ cat_rois,   // (N,5): im,x1,y1,x2,y2
    float* __restrict__ out)              // (N,256,7,7)
{
    __shared__ float rowmax[4][OUTP][LDS_W];   // 7280 B

    const int lane = threadIdx.x & 63;
    const int quad = threadIdx.x >> 6;         // wave id in block
    const int n    = blockIdx.x >> 6;          // 64 blocks per ROI
    const int c    = ((blockIdx.x & 63) << 2) + quad;

    const float* r5 = cat_rois + n * 5;
    const int im = (int)rintf(r5[0]);
    const int x1 = (int)rintf(r5[1] * 0.0625f);
    const int y1 = (int)rintf(r5[2] * 0.0625f);
    const int x2 = (int)rintf(r5[3] * 0.0625f);
    const int y2 = (int)rintf(r5[4] * 0.0625f);

    const int h = y2 - y1 + 1;   // region fully in-bounds (clamps are no-ops)
    const int w = x2 - x1 + 1;

    const float* base = features + ((size_t)(im * NCH + c)) * (FH * FW)
                                 + y1 * FW + x1;

    // ---- Phase A: per row-bin scan; coalesced row loads, one fmax each.
    //      2-row unroll with independent accumulators keeps 2 loads in flight.
    const bool active = (lane < w);
    #pragma unroll
    for (int i = 0; i < OUTP; ++i) {
        const int ys = i * h / OUTP;                       // wave-uniform
        const int ye = ((i + 1) * h + OUTP - 1) / OUTP;    // wave-uniform
        float m0 = -FLT_MAX, m1 = -FLT_MAX;
        if (active) {
            int r = ys;
            for (; r + 1 < ye; r += 2) {
                float v0 = base[r * FW + lane];
                float v1 = base[(r + 1) * FW + lane];
                m0 = fmaxf(m0, v0);
                m1 = fmaxf(m1, v1);
            }
            if (r < ye) m0 = fmaxf(m0, base[r * FW + lane]);
        }
        rowmax[quad][i][lane] = fmaxf(m0, m1);
    }

    __syncthreads();

    // ---- Phase B: 49 lanes col-pool from LDS (~3 reads avg, <=9) ----
    if (lane < OUTP * OUTP) {
        const int i  = lane / OUTP;
        const int j  = lane % OUTP;
        const int xs = j * w / OUTP;
        const int xe = ((j + 1) * w + OUTP - 1) / OUTP;    // <= w always

        float m = -FLT_MAX;
        for (int x = xs; x < xe; ++x)
            m = fmaxf(m, rowmax[quad][i][x]);

        out[(((size_t)n * NCH + c) * OUTP + i) * OUTP + j] = m;
    }
}

extern "C" void kernel_launch(void* const* d_in, const int* in_sizes, int n_in,
                              void* d_out, int out_size, void* d_ws, size_t ws_size,
                              hipStream_t stream) {
    const float* features = (const float*)d_in[0];
    const float* cat_rois = (const float*)d_in[1];
    float* out = (float*)d_out;

    const int N = in_sizes[1] / 5;        // 128 ROIs
    dim3 grid(N * (NCH / 4));             // 8192 blocks, 4 waves each
    roi_pool_v4<<<grid, 256, 0, stream>>>(features, cat_rois, out);
}

// Round 5
// 73.568 us; speedup vs baseline: 1.4281x; 1.0297x over previous
//
#include <hip/hip_runtime.h>
#include <float.h>

#define OUTP 7
#define NCH 256
#define FH 50
#define FW 50
#define LDS_W 65   // 64 lanes + 1 pad

// One wave per (roi, channel). Lane = column within ROI region.
// Fixed clamped-unroll per row-bin: bin height <= 4 rows (h<=21) or <= 8 rows
// (h<=50), proven by size = ceil((i+1)h/7)-floor(ih/7) <= floor((h+5)/7)+1.
// Clamped duplicate rows re-load the same address (L1 broadcast, ~free) in
// exchange for 28+ independent loads in flight (vs 2 in v4's dynamic loop).
// readfirstlane forces ROI params to SGPRs: bound math + row addressing on
// the scalar pipe instead of VALU.
__global__ __launch_bounds__(256) void roi_pool_v5(
    const float* __restrict__ features,   // (B,256,50,50)
    const float* __restrict__ cat_rois,   // (N,5): im,x1,y1,x2,y2
    float* __restrict__ out)              // (N,256,7,7)
{
    __shared__ float rowmax[4][OUTP][LDS_W];   // 7280 B

    const int lane = threadIdx.x & 63;
    const int quad = threadIdx.x >> 6;         // wave id in block
    const int n    = blockIdx.x >> 6;          // 64 blocks per ROI
    const int c    = ((blockIdx.x & 63) << 2) + quad;

    const float* r5 = cat_rois + n * 5;
    const int im = __builtin_amdgcn_readfirstlane((int)rintf(r5[0]));
    const int x1 = __builtin_amdgcn_readfirstlane((int)rintf(r5[1] * 0.0625f));
    const int y1 = __builtin_amdgcn_readfirstlane((int)rintf(r5[2] * 0.0625f));
    const int x2 = __builtin_amdgcn_readfirstlane((int)rintf(r5[3] * 0.0625f));
    const int y2 = __builtin_amdgcn_readfirstlane((int)rintf(r5[4] * 0.0625f));

    const int h = y2 - y1 + 1;   // region fully in-bounds (clamps are no-ops)
    const int w = x2 - x1 + 1;

    const float* base = features + ((size_t)(im * NCH + c)) * (FH * FW)
                                 + y1 * FW + x1;

    float rm[OUTP];
    #pragma unroll
    for (int i = 0; i < OUTP; ++i) rm[i] = -FLT_MAX;

    if (lane < w) {
        if (h <= 21) {
            // bin height <= 4: fixed 4 clamped loads per bin, all independent
            #pragma unroll
            for (int i = 0; i < OUTP; ++i) {
                const int ys  = i * h / OUTP;                       // uniform
                const int ye1 = ((i + 1) * h + OUTP - 1) / OUTP - 1; // >= ys
                float v0 = base[ys * FW + lane];
                float v1 = base[min(ys + 1, ye1) * FW + lane];
                float v2 = base[min(ys + 2, ye1) * FW + lane];
                float v3 = base[min(ys + 3, ye1) * FW + lane];
                rm[i] = fmaxf(fmaxf(v0, v1), fmaxf(v2, v3));
            }
        } else {
            // h in (21,50]: bin height <= 8
            #pragma unroll
            for (int i = 0; i < OUTP; ++i) {
                const int ys  = i * h / OUTP;
                const int ye1 = ((i + 1) * h + OUTP - 1) / OUTP - 1;
                float v[8];
                #pragma unroll
                for (int k = 0; k < 8; ++k)
                    v[k] = base[min(ys + k, ye1) * FW + lane];
                float m01 = fmaxf(v[0], v[1]), m23 = fmaxf(v[2], v[3]);
                float m45 = fmaxf(v[4], v[5]), m67 = fmaxf(v[6], v[7]);
                rm[i] = fmaxf(fmaxf(m01, m23), fmaxf(m45, m67));
            }
        }
    }

    #pragma unroll
    for (int i = 0; i < OUTP; ++i)
        rowmax[quad][i][lane] = rm[i];

    __syncthreads();

    // 49 lanes col-pool from LDS (~3 reads avg, <=8)
    if (lane < OUTP * OUTP) {
        const int i  = lane / OUTP;
        const int j  = lane % OUTP;
        const int xs = j * w / OUTP;
        const int xe = ((j + 1) * w + OUTP - 1) / OUTP;   // <= w always

        float m = -FLT_MAX;
        for (int x = xs; x < xe; ++x)
            m = fmaxf(m, rowmax[quad][i][x]);

        out[(((size_t)n * NCH + c) * OUTP + i) * OUTP + j] = m;
    }
}

extern "C" void kernel_launch(void* const* d_in, const int* in_sizes, int n_in,
                              void* d_out, int out_size, void* d_ws, size_t ws_size,
                              hipStream_t stream) {
    const float* features = (const float*)d_in[0];
    const float* cat_rois = (const float*)d_in[1];
    float* out = (float*)d_out;

    const int N = in_sizes[1] / 5;        // 128 ROIs
    dim3 grid(N * (NCH / 4));             // 8192 blocks, 4 waves each
    roi_pool_v5<<<grid, 256, 0, stream>>>(features, cat_rois, out);
}